// Round 6
// baseline (178.469 us; speedup 1.0000x reference)
//
#include <hip/hip_runtime.h>
#include <hip/hip_bf16.h>
#include <stdint.h>

// y[m,o] = (sum_k x[m,k]*w_int8[o,k]) * scales[o] + bias[o]
// M=2048, N=11008, K=4096.
// Round 6: same i8 256x256 BK=128 template as round 5, but deep pipeline:
// prefetch distance 2 tiles, single counted vmcnt(6) per K-tile (never drain),
// every required load has >=4 phases (~1300 cyc) before its wait.
// Stage windows (derived): B(t) reads done ph1-end -> stage B(t+2) into curB at ph2;
// A(t) reads done ph2-end -> stage A-h0(t+2) into curA at ph3; A-h1(t+1) at ph0.

typedef __attribute__((ext_vector_type(8))) short short8;
typedef __attribute__((ext_vector_type(4))) float f32x4;
typedef __attribute__((ext_vector_type(4))) float float4v;
typedef __attribute__((ext_vector_type(4))) int int4v;

#define MM 2048
#define NN 11008
#define KK 4096
#define NT (KK / 128)          // 32 K-tiles of BK=128 (i8)
#define ROWB ((size_t)KK)      // 4096 bytes per row (K in i8)

static __device__ __forceinline__ ushort f2bf_rne(float f) {
    uint32_t u = __builtin_bit_cast(uint32_t, f);
    u = (u + 0x7FFFu + ((u >> 16) & 1u)) >> 16;
    return (ushort)u;
}
static __device__ __forceinline__ ushort i2bf_exact(int v) {
    return (ushort)(__builtin_bit_cast(uint32_t, (float)v) >> 16);
}
static __device__ __forceinline__ void gload16(const void* g, void* lds) {
    __builtin_amdgcn_global_load_lds(
        (const __attribute__((address_space(1))) uint32_t*)g,
        (__attribute__((address_space(3))) uint32_t*)lds, 16, 0, 0);
}

#define BAR() do { asm volatile("" ::: "memory"); __builtin_amdgcn_s_barrier(); asm volatile("" ::: "memory"); } while (0)

// ---------------- pass 1: per-row absmax of x -> s_r, 1/s_r ----------------
__global__ __launch_bounds__(256)
void rowmax_x(const float* __restrict__ X, float* __restrict__ Sx, float* __restrict__ SxInv) {
    const int r = blockIdx.x;                   // 2048 rows
    const float4v* xr = (const float4v*)(X + (size_t)r * KK);
    float m = 0.f;
    for (int i = threadIdx.x; i < KK / 4; i += 256) {
        float4v v = xr[i];
        m = fmaxf(m, fmaxf(fmaxf(fabsf(v[0]), fabsf(v[1])),
                           fmaxf(fabsf(v[2]), fabsf(v[3]))));
    }
#pragma unroll
    for (int off = 32; off; off >>= 1) m = fmaxf(m, __shfl_down(m, off));
    __shared__ float wmax[4];
    if ((threadIdx.x & 63) == 0) wmax[threadIdx.x >> 6] = m;
    __syncthreads();
    if (threadIdx.x == 0) {
        float a = fmaxf(fmaxf(wmax[0], wmax[1]), fmaxf(wmax[2], wmax[3]));
        Sx[r]    = a / 127.f;
        SxInv[r] = (a > 0.f) ? 127.f / a : 0.f;
    }
}

// ---------------- pass 2: quantize x -> i8, pack w int32 -> i8 ----------------
__global__ __launch_bounds__(256)
void quant_pack(const float* __restrict__ X, const int* __restrict__ W,
                const float* __restrict__ SxInv,
                char* __restrict__ Xq, char* __restrict__ Wq) {
    const int NX4 = MM * KK / 4;
    const int NW4 = NN * KK / 4;
    const int stride = gridDim.x * blockDim.x;
    for (int i = blockIdx.x * blockDim.x + threadIdx.x; i < NX4 + NW4; i += stride) {
        if (i < NX4) {
            float4v v = ((const float4v*)X)[i];
            const float inv = SxInv[i >> 10];            // KK/4 = 1024 chunks/row
            uint32_t p = 0;
#pragma unroll
            for (int j = 0; j < 4; ++j) {
                int q = (int)rintf(v[j] * inv);
                p |= ((uint32_t)(q & 255)) << (8 * j);
            }
            ((uint32_t*)Xq)[i] = p;
        } else {
            int j = i - NX4;
            int4v w = ((const int4v*)W)[j];
            uint32_t p = ((uint32_t)(w[0] & 255)) | ((uint32_t)(w[1] & 255) << 8) |
                         ((uint32_t)(w[2] & 255) << 16) | ((uint32_t)(w[3] & 255) << 24);
            ((uint32_t*)Wq)[j] = p;
        }
    }
}

// stage one 128-row half-tile (2 x global_load_lds, 512 threads x 16B each)
static __device__ __forceinline__ void stage_half(const char* g, char* lhalf,
                                                  int wid, size_t ktbyte) {
    const char* s = g + ktbyte;
    char* l = lhalf + wid * 1024;
    gload16(s, l);
    gload16(s + (size_t)64 * ROWB, l + 8192);
}

// ---------------- main GEMM: 256x256 tile, BK=128 i8, deep 8-phase ----------------
__global__ __launch_bounds__(512, 2)
void gemm_256_i8(const char* __restrict__ A, const char* __restrict__ B,
                 const float* __restrict__ Sx, const float* __restrict__ S,
                 const float* __restrict__ Bv, float* __restrict__ Y) {
    __shared__ char smem[131072];   // buf0{A 32K,B 32K} buf1{A 32K,B 32K}
    char* bufA0 = smem;
    char* bufB0 = smem + 32768;
    char* bufA1 = smem + 65536;
    char* bufB1 = smem + 98304;

    const int tid  = threadIdx.x;
    const int lane = tid & 63;
    const int wid  = tid >> 6;
    const int wm   = wid >> 2;      // 2 M-waves
    const int wn   = wid & 3;       // 4 N-waves
    const int l15  = lane & 15;
    const int q    = lane >> 4;     // 0..3
    const int s7   = lane & 7;

    // XCD-aware bijective swizzle: 344 = 8*43
    const int swz  = (blockIdx.x & 7) * 43 + (blockIdx.x >> 3);
    const int brow = (swz & 7) * 256;     // 8 row-blocks
    const int bcol = (swz >> 3) * 256;    // 43 col-blocks

    // staging source (per-thread, inverse-swizzled 16B slot within 128-B row)
    const int srow  = tid >> 3;                       // 0..63
    const int sslot = (tid & 7) ^ (srow & 7);
    const char* gA0 = A + (size_t)(brow + srow) * ROWB + sslot * 16;
    const char* gA1 = gA0 + (size_t)128 * ROWB;
    const char* gB0 = B + (size_t)(bcol + srow) * ROWB + sslot * 16;
    const char* gB1 = gB0 + (size_t)128 * ROWB;

    // ds_read offsets (bytes in 32KB tile): row stride 128 B, swizzled slot
    const int rdA = (wm * 128 + l15) * 128;
    const int rdB = (wn * 64  + l15) * 128;
    const int k0  = ((q * 16)      ^ (s7 << 4));      // K 0..63 half
    const int k1  = ((64 + q * 16) ^ (s7 << 4));      // K 64..127 half

#define LDA(buf, m, koff) (*(const int4v*)((buf) + rdA + (m) * 2048 + (koff)))
#define LDB(buf, n, koff) (*(const int4v*)((buf) + rdB + (n) * 2048 + (koff)))

    int4v acc[8][4] = {};

    // ---- prologue: tile0 (8 loads) + tile1 A-h0,B-h0,B-h1 (6 loads);
    //      A-h1(tile1) is staged at ph0 of t=0. vmcnt(6) -> tile0 landed.
    stage_half(gA0, bufA0,         wid, 0);
    stage_half(gA1, bufA0 + 16384, wid, 0);
    stage_half(gB0, bufB0,         wid, 0);
    stage_half(gB1, bufB0 + 16384, wid, 0);
    stage_half(gA0, bufA1,         wid, 128);   // tile1 A-h0
    stage_half(gB0, bufB1,         wid, 128);   // tile1 B-h0
    stage_half(gB1, bufB1 + 16384, wid, 128);   // tile1 B-h1
    asm volatile("s_waitcnt vmcnt(6)" ::: "memory");
    BAR();

    char* curA = bufA0; char* curB = bufB0;
    char* nxtA = bufA1; char* nxtB = bufB1;

    for (int t = 0; t < NT; ++t) {
        const size_t kb1 = (size_t)((t + 1 < NT) ? t + 1 : NT - 1) * 128;
        const size_t kb2 = (size_t)((t + 2 < NT) ? t + 2 : NT - 1) * 128;

        int4v af[4][2], bf[4][2];

        // ---- phase 0: read A m0-3 + B n0-1 (12 reads); stage A-h1(t+1) -> nxtA hi
#pragma unroll
        for (int m = 0; m < 4; ++m) { af[m][0] = LDA(curA, m, k0); af[m][1] = LDA(curA, m, k1); }
#pragma unroll
        for (int n = 0; n < 2; ++n) { bf[n][0] = LDB(curB, n, k0); bf[n][1] = LDB(curB, n, k1); }
        stage_half(gA1, nxtA + 16384, wid, kb1);
        BAR();
        __builtin_amdgcn_s_setprio(1);
#pragma unroll
        for (int m = 0; m < 4; ++m)
#pragma unroll
            for (int n = 0; n < 2; ++n) {
                acc[m][n] = __builtin_amdgcn_mfma_i32_16x16x64_i8(af[m][0], bf[n][0], acc[m][n], 0, 0, 0);
                acc[m][n] = __builtin_amdgcn_mfma_i32_16x16x64_i8(af[m][1], bf[n][1], acc[m][n], 0, 0, 0);
            }
        __builtin_amdgcn_s_setprio(0);
        BAR();

        // ---- phase 1: read B n2-3 (4 reads); no staging
#pragma unroll
        for (int n = 2; n < 4; ++n) { bf[n][0] = LDB(curB, n, k0); bf[n][1] = LDB(curB, n, k1); }
        BAR();
        __builtin_amdgcn_s_setprio(1);
#pragma unroll
        for (int m = 0; m < 4; ++m)
#pragma unroll
            for (int n = 2; n < 4; ++n) {
                acc[m][n] = __builtin_amdgcn_mfma_i32_16x16x64_i8(af[m][0], bf[n][0], acc[m][n], 0, 0, 0);
                acc[m][n] = __builtin_amdgcn_mfma_i32_16x16x64_i8(af[m][1], bf[n][1], acc[m][n], 0, 0, 0);
            }
        __builtin_amdgcn_s_setprio(0);
        BAR();

        // ---- phase 2: read A m4-7 (8 reads); stage B(t+2) BOTH halves -> curB
        //      (all B(t) reads completed before ph1-end barrier)
#pragma unroll
        for (int m = 0; m < 4; ++m) { af[m][0] = LDA(curA, m + 4, k0); af[m][1] = LDA(curA, m + 4, k1); }
        stage_half(gB0, curB,         wid, kb2);
        stage_half(gB1, curB + 16384, wid, kb2);
        BAR();
        __builtin_amdgcn_s_setprio(1);
#pragma unroll
        for (int m = 0; m < 4; ++m)
#pragma unroll
            for (int n = 0; n < 2; ++n) {
                acc[m + 4][n] = __builtin_amdgcn_mfma_i32_16x16x64_i8(af[m][0], bf[n][0], acc[m + 4][n], 0, 0, 0);
                acc[m + 4][n] = __builtin_amdgcn_mfma_i32_16x16x64_i8(af[m][1], bf[n][1], acc[m + 4][n], 0, 0, 0);
            }
        __builtin_amdgcn_s_setprio(0);
        BAR();

        // ---- phase 3: stage A-h0(t+2) -> curA (A(t) reads done at ph2-end)
        stage_half(gA0, curA, wid, kb2);
        BAR();
        __builtin_amdgcn_s_setprio(1);
#pragma unroll
        for (int m = 0; m < 4; ++m)
#pragma unroll
            for (int n = 2; n < 4; ++n) {
                acc[m + 4][n] = __builtin_amdgcn_mfma_i32_16x16x64_i8(af[m][0], bf[n][0], acc[m + 4][n], 0, 0, 0);
                acc[m + 4][n] = __builtin_amdgcn_mfma_i32_16x16x64_i8(af[m][1], bf[n][1], acc[m + 4][n], 0, 0, 0);
            }
        __builtin_amdgcn_s_setprio(0);
        // oldest 8 of 14 outstanding = exactly tile t+1 -> landed; 6 (tile t+2) stay in flight
        asm volatile("s_waitcnt vmcnt(6)" ::: "memory");
        BAR();

        char* tA = curA; curA = nxtA; nxtA = tA;
        char* tB = curB; curB = nxtB; nxtB = tB;
    }

    // ---- epilogue: y = acc * (s_r[row] * scale[col]) + bias[col]
    // C/D: col = lane&15 (+n*16), row = q*4 + r (+m*16)
#pragma unroll
    for (int n = 0; n < 4; ++n) {
        const int gc = bcol + wn * 64 + n * 16 + l15;
        const float sj = S[gc];
        const float bj = Bv[gc];
#pragma unroll
        for (int m = 0; m < 8; ++m) {
            const int grow = brow + wm * 128 + m * 16 + q * 4;
            float* yp = Y + (size_t)grow * NN + gc;
#pragma unroll
            for (int r = 0; r < 4; ++r)
                yp[(size_t)r * NN] = (float)acc[m][n][r] * (Sx[grow + r] * sj) + bj;
        }
    }
#undef LDA
#undef LDB
}

// ---------------- fallback (round-1 fused bf16 kernel, no ws needed) ----------------
#define BMF 128
#define BKF 32
#define LDW (BKF + 8)
__global__ __launch_bounds__(256, 2)
void int8lin_fused(const float* __restrict__ X, const int* __restrict__ W,
                   const float* __restrict__ S, const float* __restrict__ Bv,
                   float* __restrict__ Y) {
    __shared__ ushort As[BMF][LDW];
    __shared__ ushort Bs[BMF][LDW];
    const int tid = threadIdx.x, lane = tid & 63, wid = tid >> 6;
    const int wm = wid >> 1, wn = wid & 1, l15 = lane & 15, kh = (lane >> 4) * 8;
    const int bm = blockIdx.x & 15, bn = blockIdx.x >> 4;
    const int brow = bm * BMF, bcol = bn * BMF;
    const int srow = tid >> 1, scol = (tid & 1) * 16;
    const float* xg = X + (size_t)(brow + srow) * KK + scol;
    const int*   wg = W + (size_t)(bcol + srow) * KK + scol;
    f32x4 acc[4][4] = {};
    for (int kt = 0; kt < KK / BKF; ++kt) {
        float4v x0 = *(const float4v*)(xg + 0), x1 = *(const float4v*)(xg + 4);
        float4v x2 = *(const float4v*)(xg + 8), x3 = *(const float4v*)(xg + 12);
        int4v w0 = *(const int4v*)(wg + 0), w1 = *(const int4v*)(wg + 4);
        int4v w2 = *(const int4v*)(wg + 8), w3 = *(const int4v*)(wg + 12);
        xg += BKF; wg += BKF;
        short8 xa = { (short)f2bf_rne(x0[0]), (short)f2bf_rne(x0[1]), (short)f2bf_rne(x0[2]), (short)f2bf_rne(x0[3]),
                      (short)f2bf_rne(x1[0]), (short)f2bf_rne(x1[1]), (short)f2bf_rne(x1[2]), (short)f2bf_rne(x1[3]) };
        short8 xb = { (short)f2bf_rne(x2[0]), (short)f2bf_rne(x2[1]), (short)f2bf_rne(x2[2]), (short)f2bf_rne(x2[3]),
                      (short)f2bf_rne(x3[0]), (short)f2bf_rne(x3[1]), (short)f2bf_rne(x3[2]), (short)f2bf_rne(x3[3]) };
        short8 wa = { (short)i2bf_exact(w0[0]), (short)i2bf_exact(w0[1]), (short)i2bf_exact(w0[2]), (short)i2bf_exact(w0[3]),
                      (short)i2bf_exact(w1[0]), (short)i2bf_exact(w1[1]), (short)i2bf_exact(w1[2]), (short)i2bf_exact(w1[3]) };
        short8 wb = { (short)i2bf_exact(w2[0]), (short)i2bf_exact(w2[1]), (short)i2bf_exact(w2[2]), (short)i2bf_exact(w2[3]),
                      (short)i2bf_exact(w3[0]), (short)i2bf_exact(w3[1]), (short)i2bf_exact(w3[2]), (short)i2bf_exact(w3[3]) };
        __syncthreads();
        *(short8*)&As[srow][scol] = xa; *(short8*)&As[srow][scol + 8] = xb;
        *(short8*)&Bs[srow][scol] = wa; *(short8*)&Bs[srow][scol + 8] = wb;
        __syncthreads();
        short8 af[4], bf4[4];
#pragma unroll
        for (int i = 0; i < 4; ++i) af[i] = *(const short8*)&As[wm * 64 + i * 16 + l15][kh];
#pragma unroll
        for (int j = 0; j < 4; ++j) bf4[j] = *(const short8*)&Bs[wn * 64 + j * 16 + l15][kh];
#pragma unroll
        for (int i = 0; i < 4; ++i)
#pragma unroll
            for (int j = 0; j < 4; ++j)
                acc[i][j] = __builtin_amdgcn_mfma_f32_16x16x32_bf16(af[i], bf4[j], acc[i][j], 0, 0, 0);
    }
#pragma unroll
    for (int j = 0; j < 4; ++j) {
        const int gc = bcol + wn * 64 + j * 16 + l15;
        const float sj = S[gc], bj = Bv[gc];
#pragma unroll
        for (int i = 0; i < 4; ++i) {
            const int grow = brow + wm * 64 + i * 16 + (lane >> 4) * 4;
            float* yp = Y + (size_t)grow * NN + gc;
#pragma unroll
            for (int r = 0; r < 4; ++r)
                yp[(size_t)r * NN] = acc[i][j][r] * sj + bj;
        }
    }
}

extern "C" void kernel_launch(void* const* d_in, const int* in_sizes, int n_in,
                              void* d_out, int out_size, void* d_ws, size_t ws_size,
                              hipStream_t stream) {
    const float* x = (const float*)d_in[0];
    const int*   w = (const int*)d_in[1];
    const float* s = (const float*)d_in[2];
    const float* b = (const float*)d_in[3];
    float* y = (float*)d_out;

    const size_t wq_b = (size_t)NN * KK;            // 45.1 MB
    const size_t xq_b = (size_t)MM * KK;            // 8.4 MB
    const size_t need = wq_b + xq_b + 2 * MM * sizeof(float) + 256;
    if (ws_size >= need) {
        char*  Wq    = (char*)d_ws;
        char*  Xq    = Wq + wq_b;
        float* Sx    = (float*)(Xq + xq_b);
        float* SxInv = Sx + MM;
        hipLaunchKernelGGL(rowmax_x,   dim3(MM),   dim3(256), 0, stream, x, Sx, SxInv);
        hipLaunchKernelGGL(quant_pack, dim3(4096), dim3(256), 0, stream, x, w, SxInv, Xq, Wq);
        hipLaunchKernelGGL(gemm_256_i8, dim3((MM / 256) * (NN / 256)), dim3(512), 0, stream,
                           Xq, Wq, Sx, s, b, y);
    } else {
        hipLaunchKernelGGL(int8lin_fused, dim3((MM / BMF) * (NN / BMF)), dim3(256), 0, stream,
                           x, w, s, b, y);
    }
}

// Round 7
// 165.324 us; speedup vs baseline: 1.0795x; 1.0795x over previous
//
#include <hip/hip_runtime.h>
#include <hip/hip_bf16.h>
#include <stdint.h>

// y[m,o] = (sum_k x[m,k]*w_int8[o,k]) * scales[o] + bias[o]
// M=2048, N=11008, K=4096.
// Round 7: i8 MFMA, tile 256x128 (8 waves x 64x64), BK=64 (64-B rows), LDS
// 48KB dbuf, VGPR<=128 -> 16 waves/CU = 2 co-resident blocks (cross-block
// overlap covers barrier stalls). Per K-tile: {8 ds_read, lgkm(0), bar,
// stage t+2 in-place (3 gload_lds), 16 MFMA, vmcnt(3), bar}. Swizzle for
// 64-B rows: slot ^= (row>>1)&3 (uniform 8 lanes/slot16 -> conflict-free).

typedef __attribute__((ext_vector_type(8))) short short8;
typedef __attribute__((ext_vector_type(4))) float f32x4;
typedef __attribute__((ext_vector_type(4))) float float4v;
typedef __attribute__((ext_vector_type(4))) int int4v;

#define MM 2048
#define NN 11008
#define KK 4096
#define NT (KK / 64)           // 64 K-tiles of BK=64 (i8) = 64 B rows
#define ROWB ((size_t)KK)      // 4096 bytes per row (K in i8)

static __device__ __forceinline__ ushort f2bf_rne(float f) {
    uint32_t u = __builtin_bit_cast(uint32_t, f);
    u = (u + 0x7FFFu + ((u >> 16) & 1u)) >> 16;
    return (ushort)u;
}
static __device__ __forceinline__ ushort i2bf_exact(int v) {
    return (ushort)(__builtin_bit_cast(uint32_t, (float)v) >> 16);
}
static __device__ __forceinline__ void gload16(const void* g, void* lds) {
    __builtin_amdgcn_global_load_lds(
        (const __attribute__((address_space(1))) uint32_t*)g,
        (__attribute__((address_space(3))) uint32_t*)lds, 16, 0, 0);
}

// ---------------- pass 1: per-row absmax of x -> s_r, 1/s_r ----------------
__global__ __launch_bounds__(256)
void rowmax_x(const float* __restrict__ X, float* __restrict__ Sx, float* __restrict__ SxInv) {
    const int r = blockIdx.x;
    const float4v* xr = (const float4v*)(X + (size_t)r * KK);
    float m = 0.f;
    for (int i = threadIdx.x; i < KK / 4; i += 256) {
        float4v v = xr[i];
        m = fmaxf(m, fmaxf(fmaxf(fabsf(v[0]), fabsf(v[1])),
                           fmaxf(fabsf(v[2]), fabsf(v[3]))));
    }
#pragma unroll
    for (int off = 32; off; off >>= 1) m = fmaxf(m, __shfl_down(m, off));
    __shared__ float wmax[4];
    if ((threadIdx.x & 63) == 0) wmax[threadIdx.x >> 6] = m;
    __syncthreads();
    if (threadIdx.x == 0) {
        float a = fmaxf(fmaxf(wmax[0], wmax[1]), fmaxf(wmax[2], wmax[3]));
        Sx[r]    = a / 127.f;
        SxInv[r] = (a > 0.f) ? 127.f / a : 0.f;
    }
}

// ---------------- pass 2: quantize x -> i8, pack w int32 -> i8 ----------------
__global__ __launch_bounds__(256)
void quant_pack(const float* __restrict__ X, const int* __restrict__ W,
                const float* __restrict__ SxInv,
                char* __restrict__ Xq, char* __restrict__ Wq) {
    const int NX4 = MM * KK / 4;
    const int NW4 = NN * KK / 4;
    const int stride = gridDim.x * blockDim.x;
    for (int i = blockIdx.x * blockDim.x + threadIdx.x; i < NX4 + NW4; i += stride) {
        if (i < NX4) {
            float4v v = ((const float4v*)X)[i];
            const float inv = SxInv[i >> 10];
            uint32_t p = 0;
#pragma unroll
            for (int j = 0; j < 4; ++j) {
                int q = (int)rintf(v[j] * inv);
                p |= ((uint32_t)(q & 255)) << (8 * j);
            }
            ((uint32_t*)Xq)[i] = p;
        } else {
            int j = i - NX4;
            int4v w = ((const int4v*)W)[j];
            uint32_t p = ((uint32_t)(w[0] & 255)) | ((uint32_t)(w[1] & 255) << 8) |
                         ((uint32_t)(w[2] & 255) << 16) | ((uint32_t)(w[3] & 255) << 24);
            ((uint32_t*)Wq)[j] = p;
        }
    }
}

// staging: A tile = 256 rows x 64 B = 16 KB (2 issues); B tile = 128 x 64 B = 8 KB (1)
static __device__ __forceinline__ void stageA(const char* g, char* lds, int wid, size_t kb) {
    gload16(g + kb,                       lds + wid * 1024);
    gload16(g + kb + (size_t)128 * ROWB,  lds + 8192 + wid * 1024);
}
static __device__ __forceinline__ void stageB(const char* g, char* lds, int wid, size_t kb) {
    gload16(g + kb, lds + wid * 1024);
}

// ---------------- main GEMM: 256x128 tile, BK=64 i8, 2 blocks/CU ----------------
__global__ __launch_bounds__(512, 4)
void gemm_i8(const char* __restrict__ A, const char* __restrict__ B,
             const float* __restrict__ Sx, const float* __restrict__ S,
             const float* __restrict__ Bv, float* __restrict__ Y) {
    __shared__ char smem[49152];          // A0 16K | A1 16K | B0 8K | B1 8K
    char* bA0 = smem;
    char* bA1 = smem + 16384;
    char* bB0 = smem + 32768;
    char* bB1 = smem + 40960;

    const int tid  = threadIdx.x;
    const int lane = tid & 63;
    const int wid  = tid >> 6;
    const int wm   = wid >> 1;            // 4 M-waves (64 rows each)
    const int wn   = wid & 1;             // 2 N-waves (64 cols each)
    const int l15  = lane & 15;
    const int q    = lane >> 4;           // k-chunk 0..3 (16 i8 each)

    // XCD-aware bijective swizzle: 688 = 8 * 86
    const int swz  = (blockIdx.x & 7) * 86 + (blockIdx.x >> 3);
    const int brow = (swz / 86) * 256;    // 8 M-tiles
    const int bcol = (swz % 86) * 128;    // 86 N-tiles

    // staging source: thread covers row tid>>2, 16-B slot (tid&3), inverse-swizzled
    const int srow4 = tid >> 2;                       // 0..127
    const int sslot = (tid & 3) ^ ((srow4 >> 1) & 3);
    const char* gA = A + (size_t)(brow + srow4) * ROWB + sslot * 16;
    const char* gB = B + (size_t)(bcol + srow4) * ROWB + sslot * 16;

    // ds_read offsets: 64-B rows; k-slot swizzle depends only on l15
    const int rdA = (wm * 64 + l15) * 64;
    const int rdB = (wn * 64 + l15) * 64;
    const int kq  = (q ^ ((l15 >> 1) & 3)) * 16;

#define LDA(buf, m) (*(const int4v*)((buf) + rdA + (m) * 1024 + kq))
#define LDB(buf, n) (*(const int4v*)((buf) + rdB + (n) * 1024 + kq))

    int4v acc[4][4] = {};

    // prologue: tile0 -> cur (3 issues), tile1 -> nxt (3); wait tile0, keep tile1 in flight
    stageA(gA, bA0, wid, 0);
    stageB(gB, bB0, wid, 0);
    stageA(gA, bA1, wid, 64);
    stageB(gB, bB1, wid, 64);
    asm volatile("s_waitcnt vmcnt(3)" ::: "memory");
    __builtin_amdgcn_s_barrier();

    char* curA = bA0; char* curB = bB0;
    char* nxtA = bA1; char* nxtB = bB1;

    for (int t = 0; t < NT; ++t) {
        const size_t kb2 = (size_t)((t + 2 < NT) ? t + 2 : NT - 1) * 64;

        int4v af[4], bf[4];
#pragma unroll
        for (int m = 0; m < 4; ++m) af[m] = LDA(curA, m);
#pragma unroll
        for (int n = 0; n < 4; ++n) bf[n] = LDB(curB, n);

        // own LDS reads retired, then all waves' reads done -> safe to overwrite cur
        asm volatile("s_waitcnt lgkmcnt(0)" ::: "memory");
        __builtin_amdgcn_s_barrier();

        // stage tile t+2 in-place into cur (3 issues, distance-2 prefetch)
        stageA(gA, curA, wid, kb2);
        stageB(gB, curB, wid, kb2);

        __builtin_amdgcn_s_setprio(1);
#pragma unroll
        for (int m = 0; m < 4; ++m)
#pragma unroll
            for (int n = 0; n < 4; ++n)
                acc[m][n] = __builtin_amdgcn_mfma_i32_16x16x64_i8(af[m], bf[n], acc[m][n], 0, 0, 0);
        __builtin_amdgcn_s_setprio(0);

        // oldest 3 of 6 outstanding = tile t+1 -> landed; t+2 stays in flight
        asm volatile("s_waitcnt vmcnt(3)" ::: "memory");
        __builtin_amdgcn_s_barrier();

        char* tA = curA; curA = nxtA; nxtA = tA;
        char* tB = curB; curB = nxtB; nxtB = tB;
    }

    // epilogue: y = acc * (s_r[row] * scale[col]) + bias[col]
    // C/D: col = lane&15 (+n*16), row = q*4 + r (+m*16)
#pragma unroll
    for (int n = 0; n < 4; ++n) {
        const int gc = bcol + wn * 64 + n * 16 + l15;
        const float sj = S[gc];
        const float bj = Bv[gc];
#pragma unroll
        for (int m = 0; m < 4; ++m) {
            const int grow = brow + wm * 64 + m * 16 + q * 4;
            float* yp = Y + (size_t)grow * NN + gc;
#pragma unroll
            for (int r = 0; r < 4; ++r)
                yp[(size_t)r * NN] = (float)acc[m][n][r] * (Sx[grow + r] * sj) + bj;
        }
    }
#undef LDA
#undef LDB
}

// ---------------- fallback (fused bf16 kernel, no ws needed) ----------------
#define BMF 128
#define BKF 32
#define LDW (BKF + 8)
__global__ __launch_bounds__(256, 2)
void int8lin_fused(const float* __restrict__ X, const int* __restrict__ W,
                   const float* __restrict__ S, const float* __restrict__ Bv,
                   float* __restrict__ Y) {
    __shared__ ushort As[BMF][LDW];
    __shared__ ushort Bs[BMF][LDW];
    const int tid = threadIdx.x, lane = tid & 63, wid = tid >> 6;
    const int wm = wid >> 1, wn = wid & 1, l15 = lane & 15, kh = (lane >> 4) * 8;
    const int bm = blockIdx.x & 15, bn = blockIdx.x >> 4;
    const int brow = bm * BMF, bcol = bn * BMF;
    const int srow = tid >> 1, scol = (tid & 1) * 16;
    const float* xg = X + (size_t)(brow + srow) * KK + scol;
    const int*   wg = W + (size_t)(bcol + srow) * KK + scol;
    f32x4 acc[4][4] = {};
    for (int kt = 0; kt < KK / BKF; ++kt) {
        float4v x0 = *(const float4v*)(xg + 0), x1 = *(const float4v*)(xg + 4);
        float4v x2 = *(const float4v*)(xg + 8), x3 = *(const float4v*)(xg + 12);
        int4v w0 = *(const int4v*)(wg + 0), w1 = *(const int4v*)(wg + 4);
        int4v w2 = *(const int4v*)(wg + 8), w3 = *(const int4v*)(wg + 12);
        xg += BKF; wg += BKF;
        short8 xa = { (short)f2bf_rne(x0[0]), (short)f2bf_rne(x0[1]), (short)f2bf_rne(x0[2]), (short)f2bf_rne(x0[3]),
                      (short)f2bf_rne(x1[0]), (short)f2bf_rne(x1[1]), (short)f2bf_rne(x1[2]), (short)f2bf_rne(x1[3]) };
        short8 xb = { (short)f2bf_rne(x2[0]), (short)f2bf_rne(x2[1]), (short)f2bf_rne(x2[2]), (short)f2bf_rne(x2[3]),
                      (short)f2bf_rne(x3[0]), (short)f2bf_rne(x3[1]), (short)f2bf_rne(x3[2]), (short)f2bf_rne(x3[3]) };
        short8 wa = { (short)i2bf_exact(w0[0]), (short)i2bf_exact(w0[1]), (short)i2bf_exact(w0[2]), (short)i2bf_exact(w0[3]),
                      (short)i2bf_exact(w1[0]), (short)i2bf_exact(w1[1]), (short)i2bf_exact(w1[2]), (short)i2bf_exact(w1[3]) };
        short8 wb = { (short)i2bf_exact(w2[0]), (short)i2bf_exact(w2[1]), (short)i2bf_exact(w2[2]), (short)i2bf_exact(w2[3]),
                      (short)i2bf_exact(w3[0]), (short)i2bf_exact(w3[1]), (short)i2bf_exact(w3[2]), (short)i2bf_exact(w3[3]) };
        __syncthreads();
        *(short8*)&As[srow][scol] = xa; *(short8*)&As[srow][scol + 8] = xb;
        *(short8*)&Bs[srow][scol] = wa; *(short8*)&Bs[srow][scol + 8] = wb;
        __syncthreads();
        short8 af[4], bf4[4];
#pragma unroll
        for (int i = 0; i < 4; ++i) af[i] = *(const short8*)&As[wm * 64 + i * 16 + l15][kh];
#pragma unroll
        for (int j = 0; j < 4; ++j) bf4[j] = *(const short8*)&Bs[wn * 64 + j * 16 + l15][kh];
#pragma unroll
        for (int i = 0; i < 4; ++i)
#pragma unroll
            for (int j = 0; j < 4; ++j)
                acc[i][j] = __builtin_amdgcn_mfma_f32_16x16x32_bf16(af[i], bf4[j], acc[i][j], 0, 0, 0);
    }
#pragma unroll
    for (int j = 0; j < 4; ++j) {
        const int gc = bcol + wn * 64 + j * 16 + l15;
        const float sj = S[gc], bj = Bv[gc];
#pragma unroll
        for (int i = 0; i < 4; ++i) {
            const int grow = brow + wm * 64 + i * 16 + (lane >> 4) * 4;
            float* yp = Y + (size_t)grow * NN + gc;
#pragma unroll
            for (int r = 0; r < 4; ++r)
                yp[(size_t)r * NN] = acc[i][j][r] * sj + bj;
        }
    }
}

extern "C" void kernel_launch(void* const* d_in, const int* in_sizes, int n_in,
                              void* d_out, int out_size, void* d_ws, size_t ws_size,
                              hipStream_t stream) {
    const float* x = (const float*)d_in[0];
    const int*   w = (const int*)d_in[1];
    const float* s = (const float*)d_in[2];
    const float* b = (const float*)d_in[3];
    float* y = (float*)d_out;

    const size_t wq_b = (size_t)NN * KK;            // 45.1 MB
    const size_t xq_b = (size_t)MM * KK;            // 8.4 MB
    const size_t need = wq_b + xq_b + 2 * MM * sizeof(float) + 256;
    if (ws_size >= need) {
        char*  Wq    = (char*)d_ws;
        char*  Xq    = Wq + wq_b;
        float* Sx    = (float*)(Xq + xq_b);
        float* SxInv = Sx + MM;
        hipLaunchKernelGGL(rowmax_x,   dim3(MM),   dim3(256), 0, stream, x, Sx, SxInv);
        hipLaunchKernelGGL(quant_pack, dim3(4096), dim3(256), 0, stream, x, w, SxInv, Xq, Wq);
        hipLaunchKernelGGL(gemm_i8, dim3((MM / 256) * (NN / 128)), dim3(512), 0, stream,
                           Xq, Wq, Sx, s, b, y);
    } else {
        hipLaunchKernelGGL(int8lin_fused, dim3((MM / BMF) * (NN / BMF)), dim3(256), 0, stream,
                           x, w, s, b, y);
    }
}